// Round 15
// baseline (183.557 us; speedup 1.0000x reference)
//
#include <hip/hip_runtime.h>
#include <hip/hip_bf16.h>

#define N_NODES 50000
#define N_EDGES 400000
#define FIN     128
#define HD      512
#define SLOPE   0.2f
#define NB_X    782    // ceil(50000/64)

typedef __hip_bfloat16 bf16;
typedef __bf16 bf16x8 __attribute__((ext_vector_type(8)));
typedef __bf16 bf16x4 __attribute__((ext_vector_type(4)));
typedef __bf16 bf16x2 __attribute__((ext_vector_type(2)));
typedef float  f32x4  __attribute__((ext_vector_type(4)));
typedef float  f32x2  __attribute__((ext_vector_type(2)));

// ---------------- sentinel (workspace too small diagnostic) ----------------
__global__ void sentinel_k(float* out, int n) {
    int i = blockIdx.x * 256 + threadIdx.x;
    if (i < n) out[i] = 12288.0f;
}

// ---- prep: zero deg+cur0 | Wfrag (fragment-ordered [W1;Wres1]) | tab | wlrb ----
__global__ __launch_bounds__(256) void prep_k(const float* __restrict__ W1, const float* __restrict__ Wres1,
                                              const float* __restrict__ al1, const float* __restrict__ ar1,
                                              const float* __restrict__ W2, const float* __restrict__ Wres2,
                                              const float* __restrict__ b1,
                                              const float* __restrict__ bnm, const float* __restrict__ bnv,
                                              const float* __restrict__ bng, const float* __restrict__ bnb,
                                              bf16* __restrict__ Wfrag, float* __restrict__ tab,
                                              bf16* __restrict__ wlrb,
                                              int* __restrict__ deg, int* __restrict__ cur0) {
    int b = blockIdx.x;
    if (b < 196) {
        int i = b * 256 + threadIdx.x;
        if (i < N_NODES) { deg[i] = 0; cur0[i] = 0; }
        return;
    }
    b -= 196;
    if (b < 64) {                        // Wfrag: 16384 fragments of 16B
        int f = b * 256 + threadIdx.x;
        int lane = f & 63, unit = f >> 6;
        int tile = unit >> 3, ks = unit & 7;
        int cl = lane & 15, rg = lane >> 4;
        int gc = tile * 16 + cl;
        int k0 = ks * 32 + rg * 8;
        bf16x8 v;
#pragma unroll
        for (int j = 0; j < 8; ++j) {
            int kk = k0 + j;
            float x = (kk < 128) ? W1[kk * HD + gc] : Wres1[(kk - 128) * HD + gc];
            v[j] = (__bf16)x;
        }
        *reinterpret_cast<bf16x8*>(reinterpret_cast<char*>(Wfrag) + (size_t)f * 16) = v;
        return;
    }
    b -= 64;
    if (b < 16) {                        // tab
        int i = b * 256 + threadIdx.x;
        int gc = i >> 3, c = i & 7;
        float v;
        if (c < 2) {
            float rs = rsqrtf(bnv[gc] + 1e-5f) * bng[gc];
            v = (c == 0) ? rs : (b1[gc] - bnm[gc]) * rs + bnb[gc];
        } else if (c < 5) {
            v = W2[gc * 3 + (c - 2)];
        } else {
            v = Wres2[gc * 3 + (c - 5)];
        }
        tab[i] = v;
        return;
    }
    // wlrb: fragment-ordered attention projections (2048 bf16)
    for (int i = 0; i < 8; ++i) {
        int e = i * 256 + threadIdx.x;
        int ks = e >> 9, lane = (e >> 3) & 63, j = e & 7;
        int r = lane & 15, rg = lane >> 4;
        int k = ks * 32 + rg * 8 + j;
        float v = 0.f;
        if (r < 4) {
            for (int d = 0; d < 128; ++d) v += W1[k * HD + r * 128 + d] * al1[r * 128 + d];
        } else if (r < 8) {
            int h = r - 4;
            for (int d = 0; d < 128; ++d) v += W1[k * HD + h * 128 + d] * ar1[h * 128 + d];
        }
        wlrb[e] = __float2bfloat16(v);
    }
}

// ---------------- eler v2: MFMA-based el/er + Xb convert | hist (tail blocks) ----------------
__global__ __launch_bounds__(256) void eler_k(const float* __restrict__ X,
                                              const bf16* __restrict__ wlrb,
                                              float* __restrict__ el, float* __restrict__ er,
                                              bf16* __restrict__ Xb,
                                              const int* __restrict__ dst, int* __restrict__ deg) {
    if (blockIdx.x >= NB_X) {            // histogram part
        int e = (blockIdx.x - NB_X) * 256 + threadIdx.x;
        if (e < N_EDGES) atomicAdd(&deg[dst[e]], 1);
        return;
    }
    __shared__ __align__(16) char XSb[64 * 256];   // 16 KB bf16, swizzled
    const int t = threadIdx.x;
    const int w = t >> 6, lane = t & 63;
    const int cl = lane & 15, rg = lane >> 4;
    const int m0 = blockIdx.x * 64;

#pragma unroll
    for (int j = 0; j < 8; ++j) {
        int e = j * 1024 + t * 4;
        int row = e >> 7, col = e & 127;
        int grow = m0 + row;
        int gc = grow < N_NODES ? grow : N_NODES - 1;
        f32x4 v = *reinterpret_cast<const f32x4*>(X + (size_t)gc * FIN + col);
        bf16x4 bv = {(__bf16)v[0], (__bf16)v[1], (__bf16)v[2], (__bf16)v[3]};
        if (grow < N_NODES)
            *reinterpret_cast<bf16x4*>(Xb + (size_t)grow * FIN + col) = bv;
        int byte = (row * 256 + col * 2) ^ ((row & 7) << 4);
        *reinterpret_cast<bf16x4*>(XSb + byte) = bv;
    }
    __syncthreads();

    f32x4 a = {0.f, 0.f, 0.f, 0.f};
    const int row = w * 16 + cl;
    const int swz = (row & 7) << 4;
#pragma unroll
    for (int ks = 0; ks < 4; ++ks) {
        bf16x8 af = *reinterpret_cast<const bf16x8*>(
            reinterpret_cast<const char*>(wlrb) + ((size_t)(ks * 64 + lane)) * 16);
        int byte = (row * 256 + ks * 64 + rg * 16) ^ swz;
        bf16x8 bf = *reinterpret_cast<const bf16x8*>(XSb + byte);
        a = __builtin_amdgcn_mfma_f32_16x16x32_bf16(af, bf, a, 0, 0, 0);
    }
    int n = m0 + row;
    if (n < N_NODES) {
        if (rg == 0)      *reinterpret_cast<float4*>(el + (size_t)n * 4) = make_float4(a[0], a[1], a[2], a[3]);
        else if (rg == 1) *reinterpret_cast<float4*>(er + (size_t)n * 4) = make_float4(a[0], a[1], a[2], a[3]);
    }
}

// 2-phase scan: rloc = block-local exclusive, blksum -> exclusive block offsets
__global__ __launch_bounds__(256) void scan1_k(const int* __restrict__ deg,
                                               int* __restrict__ rloc, int* __restrict__ blksum) {
    __shared__ int wsum[4];
    int t = threadIdx.x, b = blockIdx.x;
    int i = b * 256 + t;
    int v = (i < N_NODES) ? deg[i] : 0;
    int lane = t & 63, w = t >> 6;
    int x = v;
#pragma unroll
    for (int off = 1; off < 64; off <<= 1) {
        int y = __shfl_up(x, off);
        if (lane >= off) x += y;
    }
    if (lane == 63) wsum[w] = x;
    __syncthreads();
    int wadd = 0;
    if (w > 0) wadd += wsum[0];
    if (w > 1) wadd += wsum[1];
    if (w > 2) wadd += wsum[2];
    int incl = x + wadd;
    if (i < N_NODES) rloc[i] = incl - v;
    if (t == 255) blksum[b] = incl;
}

__global__ __launch_bounds__(256) void scan2_k(int* __restrict__ blksum) {
    __shared__ int wsum[4];
    int t = threadIdx.x;
    int v = (t < 196) ? blksum[t] : 0;
    int lane = t & 63, w = t >> 6;
    int x = v;
#pragma unroll
    for (int off = 1; off < 64; off <<= 1) {
        int y = __shfl_up(x, off);
        if (lane >= off) x += y;
    }
    if (lane == 63) wsum[w] = x;
    __syncthreads();
    int wadd = 0;
    if (w > 0) wadd += wsum[0];
    if (w > 1) wadd += wsum[1];
    if (w > 2) wadd += wsum[2];
    if (t < 196) blksum[t] = x + wadd - v;
}

// fill with inline position: csr[rloc[d]+bsum[d>>8]+slot] = src
__global__ void fill_k(const int* __restrict__ src, const int* __restrict__ dst,
                       const int* __restrict__ rloc, const int* __restrict__ bsum,
                       int* __restrict__ cur0, int* __restrict__ csr) {
    int e = blockIdx.x * 256 + threadIdx.x;
    if (e < N_EDGES) {
        int d = dst[e];
        int slot = atomicAdd(&cur0[d], 1);
        csr[rloc[d] + bsum[d >> 8] + slot] = src[e];
    }
}

// ---------------- aggX v4: 16 nodes/block, 32-lane rows (2 edges/pass), unnormalized + den4 ----------------
__global__ __launch_bounds__(1024) void aggX_k(const int* __restrict__ rloc, const int* __restrict__ bsum,
                                               const int* __restrict__ degA, const int* __restrict__ csr,
                                               const float* __restrict__ el, const float* __restrict__ er,
                                               const bf16* __restrict__ Xb, bf16* __restrict__ AGGb,
                                               float* __restrict__ den4) {
    __shared__ int    ssrc[16][64];
    __shared__ float4 spe4[16][64];

    const int w = threadIdx.x >> 6, lane = threadIdx.x & 63;
    const int sub = lane >> 5, ll = lane & 31;
    const int n = blockIdx.x * 16 + w;
    const int beg = rloc[n] + bsum[n >> 8];
    const int deg = degA[n];
    const float4 ern = *reinterpret_cast<const float4*>(er + (size_t)n * 4);
    const char* Xbc = reinterpret_cast<const char*>(Xb);

    f32x2 accA[4] = {{0.f,0.f},{0.f,0.f},{0.f,0.f},{0.f,0.f}};
    f32x2 accB[4] = {{0.f,0.f},{0.f,0.f},{0.f,0.f},{0.f,0.f}};
    float dreg = 0.f;

    for (int base = 0; base < deg; base += 64) {
        const int cnt = min(64, deg - base);
        if (lane < cnt) {
            int s = csr[beg + base + lane];
            ssrc[w][lane] = s;
            float4 e4 = *reinterpret_cast<const float4*>(el + (size_t)s * 4);
            float4 p; float e;
            e = e4.x + ern.x; e = e > 0.f ? e : SLOPE * e; p.x = __expf(e);
            e = e4.y + ern.y; e = e > 0.f ? e : SLOPE * e; p.y = __expf(e);
            e = e4.z + ern.z; e = e > 0.f ? e : SLOPE * e; p.z = __expf(e);
            e = e4.w + ern.w; e = e > 0.f ? e : SLOPE * e; p.w = __expf(e);
            spe4[w][lane] = p;
        }
        asm volatile("s_waitcnt lgkmcnt(0)" ::: "memory");
        // den partials: 4 lanes sum their head's p over the chunk (LDS broadcast reads)
        if (lane < 4) {
            for (int j = 0; j < cnt; ++j)
                dreg += reinterpret_cast<const float*>(&spe4[w][j])[lane];
        }
        // gather: 2 edges per pass (sub = which edge), 8B/lane
        for (int jj = 0; jj < cnt; jj += 2) {
            int j2 = jj + sub;
            int jc = j2 < cnt ? j2 : cnt - 1;
            int s = ssrc[w][jc];
            uint2 xv = *reinterpret_cast<const uint2*>(Xbc + (size_t)s * 256 + ll * 8);
            float4 p = spe4[w][jc];
            if (j2 >= cnt) p = make_float4(0.f, 0.f, 0.f, 0.f);
            f32x2 xlo = {__uint_as_float(xv.x << 16), __uint_as_float(xv.x & 0xffff0000u)};
            f32x2 xhi = {__uint_as_float(xv.y << 16), __uint_as_float(xv.y & 0xffff0000u)};
            accA[0] += p.x * xlo; accB[0] += p.x * xhi;
            accA[1] += p.y * xlo; accB[1] += p.y * xhi;
            accA[2] += p.z * xlo; accB[2] += p.z * xhi;
            accA[3] += p.w * xlo; accB[3] += p.w * xhi;
        }
        asm volatile("s_waitcnt lgkmcnt(0)" ::: "memory");   // WAR guard before next chunk
    }

    // cross-sub reduce (lane ^ 32)
#pragma unroll
    for (int h = 0; h < 4; ++h) {
        accA[h][0] += __shfl_xor(accA[h][0], 32);
        accA[h][1] += __shfl_xor(accA[h][1], 32);
        accB[h][0] += __shfl_xor(accB[h][0], 32);
        accB[h][1] += __shfl_xor(accB[h][1], 32);
    }
    if (sub == 0) {
#pragma unroll
        for (int h = 0; h < 4; ++h) {
            bf16x4 v = {(__bf16)accA[h][0], (__bf16)accA[h][1],
                        (__bf16)accB[h][0], (__bf16)accB[h][1]};
            *reinterpret_cast<bf16x4*>(AGGb + (size_t)n * 512 + h * 128 + ll * 4) = v;
        }
    }
    if (lane < 4) den4[(size_t)n * 4 + lane] = dreg;
}

// ---------------- gemm2 v4: coalesced Wfrag + tab; split AGG/X accumulators + inv_den epilogue ----------------
__global__ __launch_bounds__(256) void gemm2_k(
    const bf16* __restrict__ Xb, const bf16* __restrict__ AGGb,
    const float* __restrict__ den4,
    const bf16* __restrict__ Wfrag, const float* __restrict__ tab,
    const float* __restrict__ al2, const float* __restrict__ ar2,
    float* __restrict__ node2) {
    __shared__ __align__(16) char XS[32 * 256];    // 8 KB
    __shared__ __align__(16) char AGS[32 * 1024];  // 32 KB
    __shared__ float zsum[4][32][6];               // 3 KB

    const int t = threadIdx.x;
    const int w = t >> 6, lane = t & 63;
    const int cl = lane & 15, rg = lane >> 4;
    const int m0 = blockIdx.x * 32;

#pragma unroll
    for (int j = 0; j < 2; ++j) {
        int L = j * 4096 + t * 16;
        int row = L >> 8, col = L & 255;
        int grow = m0 + row; grow = grow < N_NODES ? grow : N_NODES - 1;
        bf16x8 v = *reinterpret_cast<const bf16x8*>(
            reinterpret_cast<const char*>(Xb) + (size_t)grow * 256 + col);
        int byte = (row * 256 + col) ^ ((row & 7) << 4);
        *reinterpret_cast<bf16x8*>(XS + byte) = v;
    }
#pragma unroll
    for (int j = 0; j < 8; ++j) {
        int L = j * 4096 + t * 16;
        int row = L >> 10, col = L & 1023;
        int grow = m0 + row; grow = grow < N_NODES ? grow : N_NODES - 1;
        bf16x8 v = *reinterpret_cast<const bf16x8*>(
            reinterpret_cast<const char*>(AGGb) + (size_t)grow * 1024 + col);
        int byte = (row * 1024 + col) ^ ((row & 7) << 4);
        *reinterpret_cast<bf16x8*>(AGS + byte) = v;
    }
    __syncthreads();

    // per-node inv_den for this wave's head (rows mt*16+cl)
    float invden[2];
#pragma unroll
    for (int mt = 0; mt < 2; ++mt) {
        int nn = m0 + mt * 16 + cl;
        nn = nn < N_NODES ? nn : N_NODES - 1;
        float d = den4[(size_t)nn * 4 + w];
        invden[mt] = d > 0.f ? 1.f / d : 0.f;
    }

    float z2p[2][3] = {}, r2p[2][3] = {};

#pragma unroll
    for (int ct = 0; ct < 8; ++ct) {
        const int unit = (w * 8 + ct) * 8;
        bf16x8 af[8];
#pragma unroll
        for (int ks = 0; ks < 8; ++ks)
            af[ks] = *reinterpret_cast<const bf16x8*>(
                reinterpret_cast<const char*>(Wfrag) + ((size_t)(unit + ks) * 64 + lane) * 16);
        const int gcl = w * 128 + ct * 16 + rg * 4;
        f32x4 t0[4], t1[4];
#pragma unroll
        for (int i = 0; i < 4; ++i) {
            t0[i] = *reinterpret_cast<const f32x4*>(tab + (size_t)(gcl + i) * 8);
            t1[i] = *reinterpret_cast<const f32x4*>(tab + (size_t)(gcl + i) * 8 + 4);
        }
#pragma unroll
        for (int mt = 0; mt < 2; ++mt) {
            int row = mt * 16 + cl;
            int swz = (row & 7) << 4;
            f32x4 aA = {0.f, 0.f, 0.f, 0.f};
            f32x4 aX = {0.f, 0.f, 0.f, 0.f};
#pragma unroll
            for (int ks = 0; ks < 4; ++ks) {
                int byte = (row * 1024 + w * 256 + ks * 64 + rg * 16) ^ swz;
                bf16x8 bfr = *reinterpret_cast<const bf16x8*>(AGS + byte);
                aA = __builtin_amdgcn_mfma_f32_16x16x32_bf16(af[ks], bfr, aA, 0, 0, 0);
            }
#pragma unroll
            for (int ks = 0; ks < 4; ++ks) {
                int byte = (row * 256 + ks * 64 + rg * 16) ^ swz;
                bf16x8 bfr = *reinterpret_cast<const bf16x8*>(XS + byte);
                aX = __builtin_amdgcn_mfma_f32_16x16x32_bf16(af[ks + 4], bfr, aX, 0, 0, 0);
            }
#pragma unroll
            for (int i = 0; i < 4; ++i) {
                float z = aA[i] * invden[mt] + aX[i];
                float hv = z * t0[i][0] + t0[i][1];
                hv = hv > 0.f ? hv : (__expf(hv) - 1.f);
                z2p[mt][0] += hv * t0[i][2]; z2p[mt][1] += hv * t0[i][3]; z2p[mt][2] += hv * t1[i][0];
                r2p[mt][0] += hv * t1[i][1]; r2p[mt][1] += hv * t1[i][2]; r2p[mt][2] += hv * t1[i][3];
            }
        }
    }

#pragma unroll
    for (int mt = 0; mt < 2; ++mt)
#pragma unroll
        for (int c = 0; c < 3; ++c) {
            z2p[mt][c] += __shfl_xor(z2p[mt][c], 16);
            z2p[mt][c] += __shfl_xor(z2p[mt][c], 32);
            r2p[mt][c] += __shfl_xor(r2p[mt][c], 16);
            r2p[mt][c] += __shfl_xor(r2p[mt][c], 32);
        }
    if (rg == 0) {
#pragma unroll
        for (int mt = 0; mt < 2; ++mt) {
            int nl = mt * 16 + cl;
            zsum[w][nl][0] = z2p[mt][0]; zsum[w][nl][1] = z2p[mt][1]; zsum[w][nl][2] = z2p[mt][2];
            zsum[w][nl][3] = r2p[mt][0]; zsum[w][nl][4] = r2p[mt][1]; zsum[w][nl][5] = r2p[mt][2];
        }
    }
    __syncthreads();
    if (t < 32) {
        float v[6];
#pragma unroll
        for (int c = 0; c < 6; ++c)
            v[c] = zsum[0][t][c] + zsum[1][t][c] + zsum[2][t][c] + zsum[3][t][c];
        int n = m0 + t;
        if (n < N_NODES) {
            float e2l = v[0] * al2[0] + v[1] * al2[1] + v[2] * al2[2];
            float e2r = v[0] * ar2[0] + v[1] * ar2[1] + v[2] * ar2[2];
            *reinterpret_cast<float4*>(node2 + (size_t)n * 8) = make_float4(v[0], v[1], v[2], e2l);
            *reinterpret_cast<float4*>(node2 + (size_t)n * 8 + 4) = make_float4(v[3], v[4], v[5], e2r);
        }
    }
}

// ---------------- layer-2 aggregation: wave-per-node ----------------
__global__ __launch_bounds__(256) void agg2_k(const int* __restrict__ rloc, const int* __restrict__ bsum,
                                              const int* __restrict__ degA, const int* __restrict__ csr,
                                              const float* __restrict__ node2,
                                              const float* __restrict__ b2, float* __restrict__ out) {
    int wv = threadIdx.x >> 6, lane = threadIdx.x & 63;
    int n = blockIdx.x * 4 + wv;
    int beg = rloc[n] + bsum[n >> 8];
    int deg = degA[n];
    float ern = node2[(size_t)n * 8 + 7];
    float den = 0.f, a0 = 0.f, a1 = 0.f, a2 = 0.f;
    for (int j = lane; j < deg; j += 64) {
        int s = csr[beg + j];
        float4 v = *reinterpret_cast<const float4*>(node2 + (size_t)s * 8);
        float e = v.w + ern;
        e = e > 0.f ? e : SLOPE * e;
        float p = __expf(e);
        den += p;
        a0 += p * v.x; a1 += p * v.y; a2 += p * v.z;
    }
#pragma unroll
    for (int off = 32; off > 0; off >>= 1) {
        den += __shfl_xor(den, off);
        a0 += __shfl_xor(a0, off); a1 += __shfl_xor(a1, off); a2 += __shfl_xor(a2, off);
    }
    if (lane == 0) {
        float inv = deg > 0 ? 1.f / den : 0.f;
        float4 r = *reinterpret_cast<const float4*>(node2 + (size_t)n * 8 + 4);
        out[(size_t)n * 3 + 0] = a0 * inv + r.x + b2[0];
        out[(size_t)n * 3 + 1] = a1 * inv + r.y + b2[1];
        out[(size_t)n * 3 + 2] = a2 * inv + r.z + b2[2];
    }
}

extern "C" void kernel_launch(void* const* d_in, const int* in_sizes, int n_in,
                              void* d_out, int out_size, void* d_ws, size_t ws_size,
                              hipStream_t stream) {
    const float* X     = (const float*)d_in[0];
    const int*   src   = (const int*)d_in[1];
    const int*   dst   = (const int*)d_in[2];
    const float* W1    = (const float*)d_in[3];
    const float* al1   = (const float*)d_in[4];
    const float* ar1   = (const float*)d_in[5];
    const float* b1    = (const float*)d_in[6];
    const float* Wres1 = (const float*)d_in[7];
    const float* bng   = (const float*)d_in[8];
    const float* bnb   = (const float*)d_in[9];
    const float* bnm   = (const float*)d_in[10];
    const float* bnv   = (const float*)d_in[11];
    const float* W2    = (const float*)d_in[12];
    const float* al2   = (const float*)d_in[13];
    const float* ar2   = (const float*)d_in[14];
    const float* b2    = (const float*)d_in[15];
    const float* Wres2 = (const float*)d_in[16];
    float* out = (float*)d_out;

    char* p = (char*)d_ws;
    auto carve = [&](size_t bytes) -> char* {
        char* r = p;
        p += (bytes + 255) & ~(size_t)255;
        return r;
    };
    bf16*  Wfrag  = (bf16*)carve((size_t)512 * 256 * 2);    // 256 KB fragment-ordered
    float* tab    = (float*)carve((size_t)512 * 8 * 4);     // 16 KB epilogue constants
    bf16*  wlrb   = (bf16*)carve((size_t)2048 * 2);         // 4 KB fragment-ordered wl/wr
    float* el     = (float*)carve((size_t)N_NODES * 4 * 4);
    float* er     = (float*)carve((size_t)N_NODES * 4 * 4);
    int*   deg    = (int*)carve((size_t)N_NODES * 4);
    int*   rloc   = (int*)carve((size_t)(N_NODES + 256) * 4);
    int*   cur0   = (int*)carve((size_t)N_NODES * 4);
    int*   bsum   = (int*)carve((size_t)256 * 4);
    int*   csr    = (int*)carve((size_t)N_EDGES * 4);
    bf16*  Xb     = (bf16*)carve((size_t)N_NODES * FIN * 2);
    bf16*  AGGb   = (bf16*)carve((size_t)N_NODES * 512 * 2);
    float* den4   = (float*)carve((size_t)(N_NODES + 64) * 4 * 4);
    float* node2  = (float*)carve((size_t)N_NODES * 8 * 4);
    size_t need = (size_t)(p - (char*)d_ws);
    if (need > ws_size) {
        sentinel_k<<<(out_size + 255) / 256, 256, 0, stream>>>(out, out_size);
        return;
    }

    prep_k<<<196 + 64 + 16 + 1, 256, 0, stream>>>(W1, Wres1, al1, ar1, W2, Wres2, b1,
                                                  bnm, bnv, bng, bnb, Wfrag, tab, wlrb, deg, cur0);
    eler_k<<<NB_X + (N_EDGES + 255) / 256, 256, 0, stream>>>(X, wlrb, el, er, Xb, dst, deg);
    scan1_k<<<196, 256, 0, stream>>>(deg, rloc, bsum);
    scan2_k<<<1, 256, 0, stream>>>(bsum);
    fill_k<<<(N_EDGES + 255) / 256, 256, 0, stream>>>(src, dst, rloc, bsum, cur0, csr);
    aggX_k<<<N_NODES / 16, 1024, 0, stream>>>(rloc, bsum, deg, csr, el, er, Xb, AGGb, den4);
    gemm2_k<<<(N_NODES + 31) / 32, 256, 0, stream>>>(Xb, AGGb, den4, Wfrag, tab, al2, ar2, node2);
    agg2_k<<<N_NODES / 4, 256, 0, stream>>>(rloc, bsum, deg, csr, node2, b2, out);
}

// Round 16
// 176.597 us; speedup vs baseline: 1.0394x; 1.0394x over previous
//
#include <hip/hip_runtime.h>
#include <hip/hip_bf16.h>

#define N_NODES 50000
#define N_EDGES 400000
#define FIN     128
#define HD      512
#define SLOPE   0.2f
#define NB_X    782    // ceil(50000/64)

typedef __hip_bfloat16 bf16;
typedef __bf16 bf16x8 __attribute__((ext_vector_type(8)));
typedef __bf16 bf16x4 __attribute__((ext_vector_type(4)));
typedef __bf16 bf16x2 __attribute__((ext_vector_type(2)));
typedef float  f32x4  __attribute__((ext_vector_type(4)));
typedef float  f32x2  __attribute__((ext_vector_type(2)));

// ---------------- sentinel (workspace too small diagnostic) ----------------
__global__ void sentinel_k(float* out, int n) {
    int i = blockIdx.x * 256 + threadIdx.x;
    if (i < n) out[i] = 12288.0f;
}

// ---- prep: zero deg+cur0 | Wfrag (fragment-ordered [W1;Wres1]) | tab | wlrb ----
__global__ __launch_bounds__(256) void prep_k(const float* __restrict__ W1, const float* __restrict__ Wres1,
                                              const float* __restrict__ al1, const float* __restrict__ ar1,
                                              const float* __restrict__ W2, const float* __restrict__ Wres2,
                                              const float* __restrict__ b1,
                                              const float* __restrict__ bnm, const float* __restrict__ bnv,
                                              const float* __restrict__ bng, const float* __restrict__ bnb,
                                              bf16* __restrict__ Wfrag, float* __restrict__ tab,
                                              bf16* __restrict__ wlrb,
                                              int* __restrict__ deg, int* __restrict__ cur0) {
    int b = blockIdx.x;
    if (b < 196) {
        int i = b * 256 + threadIdx.x;
        if (i < N_NODES) { deg[i] = 0; cur0[i] = 0; }
        return;
    }
    b -= 196;
    if (b < 64) {                        // Wfrag: 16384 fragments of 16B
        int f = b * 256 + threadIdx.x;
        int lane = f & 63, unit = f >> 6;
        int tile = unit >> 3, ks = unit & 7;
        int cl = lane & 15, rg = lane >> 4;
        int gc = tile * 16 + cl;
        int k0 = ks * 32 + rg * 8;
        bf16x8 v;
#pragma unroll
        for (int j = 0; j < 8; ++j) {
            int kk = k0 + j;
            float x = (kk < 128) ? W1[kk * HD + gc] : Wres1[(kk - 128) * HD + gc];
            v[j] = (__bf16)x;
        }
        *reinterpret_cast<bf16x8*>(reinterpret_cast<char*>(Wfrag) + (size_t)f * 16) = v;
        return;
    }
    b -= 64;
    if (b < 16) {                        // tab
        int i = b * 256 + threadIdx.x;
        int gc = i >> 3, c = i & 7;
        float v;
        if (c < 2) {
            float rs = rsqrtf(bnv[gc] + 1e-5f) * bng[gc];
            v = (c == 0) ? rs : (b1[gc] - bnm[gc]) * rs + bnb[gc];
        } else if (c < 5) {
            v = W2[gc * 3 + (c - 2)];
        } else {
            v = Wres2[gc * 3 + (c - 5)];
        }
        tab[i] = v;
        return;
    }
    // wlrb: fragment-ordered attention projections (2048 bf16)
    for (int i = 0; i < 8; ++i) {
        int e = i * 256 + threadIdx.x;
        int ks = e >> 9, lane = (e >> 3) & 63, j = e & 7;
        int r = lane & 15, rg = lane >> 4;
        int k = ks * 32 + rg * 8 + j;
        float v = 0.f;
        if (r < 4) {
            for (int d = 0; d < 128; ++d) v += W1[k * HD + r * 128 + d] * al1[r * 128 + d];
        } else if (r < 8) {
            int h = r - 4;
            for (int d = 0; d < 128; ++d) v += W1[k * HD + h * 128 + d] * ar1[h * 128 + d];
        }
        wlrb[e] = __float2bfloat16(v);
    }
}

// ---------------- eler v2: MFMA-based el/er + Xb convert | hist (tail blocks) ----------------
__global__ __launch_bounds__(256) void eler_k(const float* __restrict__ X,
                                              const bf16* __restrict__ wlrb,
                                              float* __restrict__ el, float* __restrict__ er,
                                              bf16* __restrict__ Xb,
                                              const int* __restrict__ dst, int* __restrict__ deg) {
    if (blockIdx.x >= NB_X) {            // histogram part
        int e = (blockIdx.x - NB_X) * 256 + threadIdx.x;
        if (e < N_EDGES) atomicAdd(&deg[dst[e]], 1);
        return;
    }
    __shared__ __align__(16) char XSb[64 * 256];   // 16 KB bf16, swizzled
    const int t = threadIdx.x;
    const int w = t >> 6, lane = t & 63;
    const int cl = lane & 15, rg = lane >> 4;
    const int m0 = blockIdx.x * 64;

#pragma unroll
    for (int j = 0; j < 8; ++j) {
        int e = j * 1024 + t * 4;
        int row = e >> 7, col = e & 127;
        int grow = m0 + row;
        int gc = grow < N_NODES ? grow : N_NODES - 1;
        f32x4 v = *reinterpret_cast<const f32x4*>(X + (size_t)gc * FIN + col);
        bf16x4 bv = {(__bf16)v[0], (__bf16)v[1], (__bf16)v[2], (__bf16)v[3]};
        if (grow < N_NODES)
            *reinterpret_cast<bf16x4*>(Xb + (size_t)grow * FIN + col) = bv;
        int byte = (row * 256 + col * 2) ^ ((row & 7) << 4);
        *reinterpret_cast<bf16x4*>(XSb + byte) = bv;
    }
    __syncthreads();

    f32x4 a = {0.f, 0.f, 0.f, 0.f};
    const int row = w * 16 + cl;
    const int swz = (row & 7) << 4;
#pragma unroll
    for (int ks = 0; ks < 4; ++ks) {
        bf16x8 af = *reinterpret_cast<const bf16x8*>(
            reinterpret_cast<const char*>(wlrb) + ((size_t)(ks * 64 + lane)) * 16);
        int byte = (row * 256 + ks * 64 + rg * 16) ^ swz;
        bf16x8 bf = *reinterpret_cast<const bf16x8*>(XSb + byte);
        a = __builtin_amdgcn_mfma_f32_16x16x32_bf16(af, bf, a, 0, 0, 0);
    }
    int n = m0 + row;
    if (n < N_NODES) {
        if (rg == 0)      *reinterpret_cast<float4*>(el + (size_t)n * 4) = make_float4(a[0], a[1], a[2], a[3]);
        else if (rg == 1) *reinterpret_cast<float4*>(er + (size_t)n * 4) = make_float4(a[0], a[1], a[2], a[3]);
    }
}

// 2-phase scan: rloc = block-local exclusive, blksum -> exclusive block offsets
__global__ __launch_bounds__(256) void scan1_k(const int* __restrict__ deg,
                                               int* __restrict__ rloc, int* __restrict__ blksum) {
    __shared__ int wsum[4];
    int t = threadIdx.x, b = blockIdx.x;
    int i = b * 256 + t;
    int v = (i < N_NODES) ? deg[i] : 0;
    int lane = t & 63, w = t >> 6;
    int x = v;
#pragma unroll
    for (int off = 1; off < 64; off <<= 1) {
        int y = __shfl_up(x, off);
        if (lane >= off) x += y;
    }
    if (lane == 63) wsum[w] = x;
    __syncthreads();
    int wadd = 0;
    if (w > 0) wadd += wsum[0];
    if (w > 1) wadd += wsum[1];
    if (w > 2) wadd += wsum[2];
    int incl = x + wadd;
    if (i < N_NODES) rloc[i] = incl - v;
    if (t == 255) blksum[b] = incl;
}

__global__ __launch_bounds__(256) void scan2_k(int* __restrict__ blksum) {
    __shared__ int wsum[4];
    int t = threadIdx.x;
    int v = (t < 196) ? blksum[t] : 0;
    int lane = t & 63, w = t >> 6;
    int x = v;
#pragma unroll
    for (int off = 1; off < 64; off <<= 1) {
        int y = __shfl_up(x, off);
        if (lane >= off) x += y;
    }
    if (lane == 63) wsum[w] = x;
    __syncthreads();
    int wadd = 0;
    if (w > 0) wadd += wsum[0];
    if (w > 1) wadd += wsum[1];
    if (w > 2) wadd += wsum[2];
    if (t < 196) blksum[t] = x + wadd - v;
}

// fill with inline position: csr[rloc[d]+bsum[d>>8]+slot] = src
__global__ void fill_k(const int* __restrict__ src, const int* __restrict__ dst,
                       const int* __restrict__ rloc, const int* __restrict__ bsum,
                       int* __restrict__ cur0, int* __restrict__ csr) {
    int e = blockIdx.x * 256 + threadIdx.x;
    if (e < N_EDGES) {
        int d = dst[e];
        int slot = atomicAdd(&cur0[d], 1);
        csr[rloc[d] + bsum[d >> 8] + slot] = src[e];
    }
}

// ---------------- aggX v5: node-per-half, LDS-free, shuffle-broadcast gather ----------------
// Half (32 lanes) owns one node; lane ll owns channels ll*4..+3 (8B). Per edge j:
// s_j / p_j broadcast via __shfl from lane sub*32+j. Xb gathers depend only on csr -> overlap el/exp.
__global__ __launch_bounds__(1024) void aggX_k(const int* __restrict__ rloc, const int* __restrict__ bsum,
                                               const int* __restrict__ degA, const int* __restrict__ csr,
                                               const float* __restrict__ el, const float* __restrict__ er,
                                               const bf16* __restrict__ Xb, bf16* __restrict__ AGGb,
                                               float* __restrict__ den4) {
    const int w = threadIdx.x >> 6, lane = threadIdx.x & 63;
    const int sub = lane >> 5, ll = lane & 31;
    int n = blockIdx.x * 32 + w * 2 + sub;
    const bool valid = n < N_NODES;
    if (!valid) n = N_NODES - 1;
    const int beg = rloc[n] + bsum[n >> 8];
    const int deg = degA[n];
    const float4 ern = *reinterpret_cast<const float4*>(er + (size_t)n * 4);
    const char* Xbc = reinterpret_cast<const char*>(Xb);

    f32x2 accA[4] = {{0.f,0.f},{0.f,0.f},{0.f,0.f},{0.f,0.f}};
    f32x2 accB[4] = {{0.f,0.f},{0.f,0.f},{0.f,0.f},{0.f,0.f}};
    float4 dp = make_float4(0.f, 0.f, 0.f, 0.f);

    for (int base = 0; base < deg; base += 32) {
        const int cnt = min(32, deg - base);
        int s = 0;
        if (ll < cnt) s = csr[beg + base + ll];
        // el load + exp on owner lanes (overlaps with gather loads below via compiler scheduling)
        float4 e4 = *reinterpret_cast<const float4*>(el + (size_t)s * 4);
        float4 p; float e;
        e = e4.x + ern.x; e = e > 0.f ? e : SLOPE * e; p.x = __expf(e);
        e = e4.y + ern.y; e = e > 0.f ? e : SLOPE * e; p.y = __expf(e);
        e = e4.z + ern.z; e = e > 0.f ? e : SLOPE * e; p.z = __expf(e);
        e = e4.w + ern.w; e = e > 0.f ? e : SLOPE * e; p.w = __expf(e);

        for (int j = 0; j < cnt; ++j) {
            int idx = sub * 32 + j;
            int sj = __shfl(s, idx);
            uint2 xv = *reinterpret_cast<const uint2*>(Xbc + (size_t)sj * 256 + ll * 8);
            float4 pj;
            pj.x = __shfl(p.x, idx);
            pj.y = __shfl(p.y, idx);
            pj.z = __shfl(p.z, idx);
            pj.w = __shfl(p.w, idx);
            dp.x += pj.x; dp.y += pj.y; dp.z += pj.z; dp.w += pj.w;
            f32x2 xlo = {__uint_as_float(xv.x << 16), __uint_as_float(xv.x & 0xffff0000u)};
            f32x2 xhi = {__uint_as_float(xv.y << 16), __uint_as_float(xv.y & 0xffff0000u)};
            accA[0] += pj.x * xlo; accB[0] += pj.x * xhi;
            accA[1] += pj.y * xlo; accB[1] += pj.y * xhi;
            accA[2] += pj.z * xlo; accB[2] += pj.z * xhi;
            accA[3] += pj.w * xlo; accB[3] += pj.w * xhi;
        }
    }

    if (valid) {
#pragma unroll
        for (int h = 0; h < 4; ++h) {
            bf16x4 v = {(__bf16)accA[h][0], (__bf16)accA[h][1],
                        (__bf16)accB[h][0], (__bf16)accB[h][1]};
            *reinterpret_cast<bf16x4*>(AGGb + (size_t)n * 512 + h * 128 + ll * 4) = v;
        }
        if (ll == 0) *reinterpret_cast<float4*>(den4 + (size_t)n * 4) = dp;
    }
}

// ---------------- gemm2 v4: coalesced Wfrag + tab; split AGG/X accumulators + inv_den epilogue ----------------
__global__ __launch_bounds__(256) void gemm2_k(
    const bf16* __restrict__ Xb, const bf16* __restrict__ AGGb,
    const float* __restrict__ den4,
    const bf16* __restrict__ Wfrag, const float* __restrict__ tab,
    const float* __restrict__ al2, const float* __restrict__ ar2,
    float* __restrict__ node2) {
    __shared__ __align__(16) char XS[32 * 256];    // 8 KB
    __shared__ __align__(16) char AGS[32 * 1024];  // 32 KB
    __shared__ float zsum[4][32][6];               // 3 KB

    const int t = threadIdx.x;
    const int w = t >> 6, lane = t & 63;
    const int cl = lane & 15, rg = lane >> 4;
    const int m0 = blockIdx.x * 32;

#pragma unroll
    for (int j = 0; j < 2; ++j) {
        int L = j * 4096 + t * 16;
        int row = L >> 8, col = L & 255;
        int grow = m0 + row; grow = grow < N_NODES ? grow : N_NODES - 1;
        bf16x8 v = *reinterpret_cast<const bf16x8*>(
            reinterpret_cast<const char*>(Xb) + (size_t)grow * 256 + col);
        int byte = (row * 256 + col) ^ ((row & 7) << 4);
        *reinterpret_cast<bf16x8*>(XS + byte) = v;
    }
#pragma unroll
    for (int j = 0; j < 8; ++j) {
        int L = j * 4096 + t * 16;
        int row = L >> 10, col = L & 1023;
        int grow = m0 + row; grow = grow < N_NODES ? grow : N_NODES - 1;
        bf16x8 v = *reinterpret_cast<const bf16x8*>(
            reinterpret_cast<const char*>(AGGb) + (size_t)grow * 1024 + col);
        int byte = (row * 1024 + col) ^ ((row & 7) << 4);
        *reinterpret_cast<bf16x8*>(AGS + byte) = v;
    }
    __syncthreads();

    // per-node inv_den for this wave's head (rows mt*16+cl)
    float invden[2];
#pragma unroll
    for (int mt = 0; mt < 2; ++mt) {
        int nn = m0 + mt * 16 + cl;
        nn = nn < N_NODES ? nn : N_NODES - 1;
        float d = den4[(size_t)nn * 4 + w];
        invden[mt] = d > 0.f ? 1.f / d : 0.f;
    }

    float z2p[2][3] = {}, r2p[2][3] = {};

#pragma unroll
    for (int ct = 0; ct < 8; ++ct) {
        const int unit = (w * 8 + ct) * 8;
        bf16x8 af[8];
#pragma unroll
        for (int ks = 0; ks < 8; ++ks)
            af[ks] = *reinterpret_cast<const bf16x8*>(
                reinterpret_cast<const char*>(Wfrag) + ((size_t)(unit + ks) * 64 + lane) * 16);
        const int gcl = w * 128 + ct * 16 + rg * 4;
        f32x4 t0[4], t1[4];
#pragma unroll
        for (int i = 0; i < 4; ++i) {
            t0[i] = *reinterpret_cast<const f32x4*>(tab + (size_t)(gcl + i) * 8);
            t1[i] = *reinterpret_cast<const f32x4*>(tab + (size_t)(gcl + i) * 8 + 4);
        }
#pragma unroll
        for (int mt = 0; mt < 2; ++mt) {
            int row = mt * 16 + cl;
            int swz = (row & 7) << 4;
            f32x4 aA = {0.f, 0.f, 0.f, 0.f};
            f32x4 aX = {0.f, 0.f, 0.f, 0.f};
#pragma unroll
            for (int ks = 0; ks < 4; ++ks) {
                int byte = (row * 1024 + w * 256 + ks * 64 + rg * 16) ^ swz;
                bf16x8 bfr = *reinterpret_cast<const bf16x8*>(AGS + byte);
                aA = __builtin_amdgcn_mfma_f32_16x16x32_bf16(af[ks], bfr, aA, 0, 0, 0);
            }
#pragma unroll
            for (int ks = 0; ks < 4; ++ks) {
                int byte = (row * 256 + ks * 64 + rg * 16) ^ swz;
                bf16x8 bfr = *reinterpret_cast<const bf16x8*>(XS + byte);
                aX = __builtin_amdgcn_mfma_f32_16x16x32_bf16(af[ks + 4], bfr, aX, 0, 0, 0);
            }
#pragma unroll
            for (int i = 0; i < 4; ++i) {
                float z = aA[i] * invden[mt] + aX[i];
                float hv = z * t0[i][0] + t0[i][1];
                hv = hv > 0.f ? hv : (__expf(hv) - 1.f);
                z2p[mt][0] += hv * t0[i][2]; z2p[mt][1] += hv * t0[i][3]; z2p[mt][2] += hv * t1[i][0];
                r2p[mt][0] += hv * t1[i][1]; r2p[mt][1] += hv * t1[i][2]; r2p[mt][2] += hv * t1[i][3];
            }
        }
    }

#pragma unroll
    for (int mt = 0; mt < 2; ++mt)
#pragma unroll
        for (int c = 0; c < 3; ++c) {
            z2p[mt][c] += __shfl_xor(z2p[mt][c], 16);
            z2p[mt][c] += __shfl_xor(z2p[mt][c], 32);
            r2p[mt][c] += __shfl_xor(r2p[mt][c], 16);
            r2p[mt][c] += __shfl_xor(r2p[mt][c], 32);
        }
    if (rg == 0) {
#pragma unroll
        for (int mt = 0; mt < 2; ++mt) {
            int nl = mt * 16 + cl;
            zsum[w][nl][0] = z2p[mt][0]; zsum[w][nl][1] = z2p[mt][1]; zsum[w][nl][2] = z2p[mt][2];
            zsum[w][nl][3] = r2p[mt][0]; zsum[w][nl][4] = r2p[mt][1]; zsum[w][nl][5] = r2p[mt][2];
        }
    }
    __syncthreads();
    if (t < 32) {
        float v[6];
#pragma unroll
        for (int c = 0; c < 6; ++c)
            v[c] = zsum[0][t][c] + zsum[1][t][c] + zsum[2][t][c] + zsum[3][t][c];
        int n = m0 + t;
        if (n < N_NODES) {
            float e2l = v[0] * al2[0] + v[1] * al2[1] + v[2] * al2[2];
            float e2r = v[0] * ar2[0] + v[1] * ar2[1] + v[2] * ar2[2];
            *reinterpret_cast<float4*>(node2 + (size_t)n * 8) = make_float4(v[0], v[1], v[2], e2l);
            *reinterpret_cast<float4*>(node2 + (size_t)n * 8 + 4) = make_float4(v[3], v[4], v[5], e2r);
        }
    }
}

// ---------------- layer-2 aggregation: wave-per-node ----------------
__global__ __launch_bounds__(256) void agg2_k(const int* __restrict__ rloc, const int* __restrict__ bsum,
                                              const int* __restrict__ degA, const int* __restrict__ csr,
                                              const float* __restrict__ node2,
                                              const float* __restrict__ b2, float* __restrict__ out) {
    int wv = threadIdx.x >> 6, lane = threadIdx.x & 63;
    int n = blockIdx.x * 4 + wv;
    int beg = rloc[n] + bsum[n >> 8];
    int deg = degA[n];
    float ern = node2[(size_t)n * 8 + 7];
    float den = 0.f, a0 = 0.f, a1 = 0.f, a2 = 0.f;
    for (int j = lane; j < deg; j += 64) {
        int s = csr[beg + j];
        float4 v = *reinterpret_cast<const float4*>(node2 + (size_t)s * 8);
        float e = v.w + ern;
        e = e > 0.f ? e : SLOPE * e;
        float p = __expf(e);
        den += p;
        a0 += p * v.x; a1 += p * v.y; a2 += p * v.z;
    }
#pragma unroll
    for (int off = 32; off > 0; off >>= 1) {
        den += __shfl_xor(den, off);
        a0 += __shfl_xor(a0, off); a1 += __shfl_xor(a1, off); a2 += __shfl_xor(a2, off);
    }
    if (lane == 0) {
        float inv = deg > 0 ? 1.f / den : 0.f;
        float4 r = *reinterpret_cast<const float4*>(node2 + (size_t)n * 8 + 4);
        out[(size_t)n * 3 + 0] = a0 * inv + r.x + b2[0];
        out[(size_t)n * 3 + 1] = a1 * inv + r.y + b2[1];
        out[(size_t)n * 3 + 2] = a2 * inv + r.z + b2[2];
    }
}

extern "C" void kernel_launch(void* const* d_in, const int* in_sizes, int n_in,
                              void* d_out, int out_size, void* d_ws, size_t ws_size,
                              hipStream_t stream) {
    const float* X     = (const float*)d_in[0];
    const int*   src   = (const int*)d_in[1];
    const int*   dst   = (const int*)d_in[2];
    const float* W1    = (const float*)d_in[3];
    const float* al1   = (const float*)d_in[4];
    const float* ar1   = (const float*)d_in[5];
    const float* b1    = (const float*)d_in[6];
    const float* Wres1 = (const float*)d_in[7];
    const float* bng   = (const float*)d_in[8];
    const float* bnb   = (const float*)d_in[9];
    const float* bnm   = (const float*)d_in[10];
    const float* bnv   = (const float*)d_in[11];
    const float* W2    = (const float*)d_in[12];
    const float* al2   = (const float*)d_in[13];
    const float* ar2   = (const float*)d_in[14];
    const float* b2    = (const float*)d_in[15];
    const float* Wres2 = (const float*)d_in[16];
    float* out = (float*)d_out;

    char* p = (char*)d_ws;
    auto carve = [&](size_t bytes) -> char* {
        char* r = p;
        p += (bytes + 255) & ~(size_t)255;
        return r;
    };
    bf16*  Wfrag  = (bf16*)carve((size_t)512 * 256 * 2);    // 256 KB fragment-ordered
    float* tab    = (float*)carve((size_t)512 * 8 * 4);     // 16 KB epilogue constants
    bf16*  wlrb   = (bf16*)carve((size_t)2048 * 2);         // 4 KB fragment-ordered wl/wr
    float* el     = (float*)carve((size_t)N_NODES * 4 * 4);
    float* er     = (float*)carve((size_t)N_NODES * 4 * 4);
    int*   deg    = (int*)carve((size_t)N_NODES * 4);
    int*   rloc   = (int*)carve((size_t)(N_NODES + 256) * 4);
    int*   cur0   = (int*)carve((size_t)N_NODES * 4);
    int*   bsum   = (int*)carve((size_t)256 * 4);
    int*   csr    = (int*)carve((size_t)N_EDGES * 4);
    bf16*  Xb     = (bf16*)carve((size_t)N_NODES * FIN * 2);
    bf16*  AGGb   = (bf16*)carve((size_t)N_NODES * 512 * 2);
    float* den4   = (float*)carve((size_t)(N_NODES + 64) * 4 * 4);
    float* node2  = (float*)carve((size_t)N_NODES * 8 * 4);
    size_t need = (size_t)(p - (char*)d_ws);
    if (need > ws_size) {
        sentinel_k<<<(out_size + 255) / 256, 256, 0, stream>>>(out, out_size);
        return;
    }

    prep_k<<<196 + 64 + 16 + 1, 256, 0, stream>>>(W1, Wres1, al1, ar1, W2, Wres2, b1,
                                                  bnm, bnv, bng, bnb, Wfrag, tab, wlrb, deg, cur0);
    eler_k<<<NB_X + (N_EDGES + 255) / 256, 256, 0, stream>>>(X, wlrb, el, er, Xb, dst, deg);
    scan1_k<<<196, 256, 0, stream>>>(deg, rloc, bsum);
    scan2_k<<<1, 256, 0, stream>>>(bsum);
    fill_k<<<(N_EDGES + 255) / 256, 256, 0, stream>>>(src, dst, rloc, bsum, cur0, csr);
    aggX_k<<<(N_NODES + 31) / 32, 1024, 0, stream>>>(rloc, bsum, deg, csr, el, er, Xb, AGGb, den4);
    gemm2_k<<<(N_NODES + 31) / 32, 256, 0, stream>>>(Xb, AGGb, den4, Wfrag, tab, al2, ar2, node2);
    agg2_k<<<N_NODES / 4, 256, 0, stream>>>(rloc, bsum, deg, csr, node2, b2, out);
}